// Round 6
// baseline (539.395 us; speedup 1.0000x reference)
//
#include <hip/hip_runtime.h>

#define DIMN 2048
#define RANKN 128
#define TT 1024
#define BBATCH 16
#define BD (BBATCH * DIMN)   // 32768 elements per timestep slice
#define CH 16                // scan chunk length (t-steps)
#define NCH (TT / CH)        // 64 chunks
#define PITW 66              // wwd row pitch in floats (32*2 interleaved + 2)
#define PITH 36              // hs row pitch in floats (16B-aligned rows)

typedef __attribute__((ext_vector_type(4))) float floatx4;
typedef __attribute__((ext_vector_type(8))) short short8;

// fp32 -> bf16 round-to-nearest-even on raw bits
__device__ __forceinline__ short f2bf(float f) {
    unsigned u = __float_as_uint(f);
    unsigned r = (u + 0x7FFFu + ((u >> 16) & 1u)) >> 16;
    return (short)r;
}
// rcp-based activations: v_rcp_f32 (~1 ulp) instead of the ~10-instr exact
// division sequence — removes ~60-80 cy from every serial scan step.
__device__ __forceinline__ float fast_sigmoid(float z) {
    return __builtin_amdgcn_rcpf(1.0f + __expf(-z));
}
__device__ __forceinline__ float fast_tanh(float z) {
    return 1.0f - 2.0f * __builtin_amdgcn_rcpf(__expf(2.0f * z) + 1.0f);
}

// ---------------------------------------------------------------------------
// Prep: V_x|V_d -> bf16 Vb[256][2048] (rows 0..127 = V_x, 128..255 = V_d).
// ---------------------------------------------------------------------------
__global__ __launch_bounds__(256)
void prep_vb(const float* __restrict__ Vx, const float* __restrict__ Vd,
             short* __restrict__ Vb) {
    const int gid = blockIdx.x * 256 + threadIdx.x;     // 0..65535
    const size_t base = (size_t)gid * 8;
    const size_t half = (size_t)RANKN * DIMN;           // 262144
    const float* src = (base < half) ? Vx : Vd;
    const size_t off = (base < half) ? base : (base - half);
    float4 a = *(const float4*)(src + off);
    float4 c = *(const float4*)(src + off + 4);
    short8 v;
    v[0] = f2bf(a.x); v[1] = f2bf(a.y); v[2] = f2bf(a.z); v[3] = f2bf(a.w);
    v[4] = f2bf(c.x); v[5] = f2bf(c.y); v[6] = f2bf(c.z); v[7] = f2bf(c.w);
    *(short8*)(Vb + base) = v;
}

// ---------------------------------------------------------------------------
// Phase 1: xvb = x @ [V_x^T | V_d^T] as bf16 [16384][256]. (R2 version —
// fastest measured variant.) M-tile 32 -> 512 blocks = 2/CU.
// ---------------------------------------------------------------------------
__global__ __launch_bounds__(256, 2)
void gemm_xv(const float* __restrict__ X, const short* __restrict__ Vb,
             short* __restrict__ xvb) {
    constexpr int PADK = 40;
    __shared__ short As[32 * PADK];
    __shared__ short Bs[2][128 * PADK];

    const int m0 = blockIdx.x * 32;
    const int tid = threadIdx.x;
    const int wave = tid >> 6;
    const int lane = tid & 63;
    const int lr = lane & 15;
    const int q  = lane >> 4;
    const int mat = wave >> 1;
    const int wn  = (wave & 1) * 64;

    floatx4 acc[2][4] = {};

    for (int k0 = 0; k0 < DIMN; k0 += 32) {
        {
            int r = tid >> 3, c = (tid & 7) * 4;
            float4 v = *(const float4*)(X + (size_t)(m0 + r) * DIMN + k0 + c);
            *(short4*)&As[r * PADK + c] =
                make_short4(f2bf(v.x), f2bf(v.y), f2bf(v.z), f2bf(v.w));
        }
        #pragma unroll
        for (int i = 0; i < 4; ++i) {
            int u = tid + i * 256;
            int bm = u >> 9;
            int rem = u & 511;
            int r = rem >> 2, c8 = (rem & 3) * 8;
            short8 v = *(const short8*)(Vb + ((size_t)bm * RANKN + r) * DIMN + k0 + c8);
            *(short8*)&Bs[bm][r * PADK + c8] = v;
        }
        __syncthreads();

        short8 af[2], bfr[4];
        #pragma unroll
        for (int mi = 0; mi < 2; ++mi)
            af[mi] = *(const short8*)&As[(mi * 16 + lr) * PADK + q * 8];
        #pragma unroll
        for (int nj = 0; nj < 4; ++nj)
            bfr[nj] = *(const short8*)&Bs[mat][(wn + nj * 16 + lr) * PADK + q * 8];

        #pragma unroll
        for (int mi = 0; mi < 2; ++mi)
            #pragma unroll
            for (int nj = 0; nj < 4; ++nj)
                acc[mi][nj] = __builtin_amdgcn_mfma_f32_16x16x32_bf16(
                    af[mi], bfr[nj], acc[mi][nj], 0, 0, 0);
        __syncthreads();
    }

    #pragma unroll
    for (int mi = 0; mi < 2; ++mi)
        #pragma unroll
        for (int nj = 0; nj < 4; ++nj)
            #pragma unroll
            for (int r = 0; r < 4; ++r) {
                int row = m0 + mi * 16 + q * 4 + r;
                int col = mat * RANKN + wn + nj * 16 + lr;
                xvb[(size_t)row * 256 + col] = f2bf(acc[mi][nj][r]);
            }
}

// ---------------------------------------------------------------------------
// Phase 2+3 fused: 3-wave role pipeline, d-chunk = 32, 1024 blocks = 4/CU
// (12 waves/CU — R5 measured only 2 store-issuing waves/CU and 1.56 TB/s of
// write throughput; doubling pipelines/CU doubles memory-level parallelism).
// Depth-4 LDS ring buffers decouple the roles; LDS-counter sync, no barriers.
//   wave0 (chain):    ds_read_b64 (wx,wd interleaved) x16, free buf, 16-step
//                     rcp-based serial chain, ds_write h, signal.
//   wave1 (producer): U frags (16 short8 = 64 VGPR) + xvb frags in regs;
//                     16 MFMA -> wwd ring slot; global prefetch 1 chunk ahead.
//   wave2 (flusher):  read h (b128), gate, 4 float4 stores/lane/chunk;
//                     x prefetched 1 chunk ahead.
// LDS: wwd 4x16x66x4 = 16.9KB + hs 4x16x36x4 = 9.2KB + cnt = ~26KB.
// ---------------------------------------------------------------------------
#define SPIN(ctr, tgt) \
    while (((volatile int*)cnt)[ctr] < (tgt)) __builtin_amdgcn_s_sleep(1); \
    asm volatile("" ::: "memory");

#define SIGNAL(ctr, val) \
    asm volatile("" ::: "memory"); \
    if (lane == 0) ((volatile int*)cnt)[ctr] = (val);

#define SIGNAL_AFTER_READS(ctr, val) \
    asm volatile("s_waitcnt lgkmcnt(0)" ::: "memory"); \
    if (lane == 0) ((volatile int*)cnt)[ctr] = (val);

__global__ __launch_bounds__(192, 3)
void fused_scan(const short* __restrict__ xvb, const float* __restrict__ x,
                const float* __restrict__ h0,
                const float* __restrict__ Ux, const float* __restrict__ Ud,
                const float* __restrict__ r_h, const float* __restrict__ r_delta,
                const float* __restrict__ bvec, const float* __restrict__ b_delta,
                const float* __restrict__ b_gate,
                float* __restrict__ obuf, float* __restrict__ hbuf) {
    __shared__ float wwds[4 * CH * PITW];   // [slot][t][dcol*2 + mat]
    __shared__ float hsd [4 * CH * PITH];   // [slot][t][dcol]
    __shared__ int cnt[4];                  // 0:fill 1:wfree 2:hready 3:hfree

    const int id   = blockIdx.x;            // 0..1023
    const int xcd  = id & 7;
    const int slot = id >> 3;               // 0..127
    const int b  = xcd * 2 + (slot & 1);
    const int d0 = (slot >> 1) * 32;

    const int tid  = threadIdx.x;
    const int wave = tid >> 6;
    const int lane = tid & 63;
    const int lr = lane & 15;
    const int q  = lane >> 4;

    if (tid == 0) { cnt[0] = 0; cnt[1] = 0; cnt[2] = 0; cnt[3] = 0; }
    __syncthreads();                        // the only barrier

    if (wave == 1) {
        // ---------------- producer ----------------
        // U fragments in registers (B-operand layout: lane holds U-row
        // d0+nj*16+lr, k = ks*32 + q*8 .. +8). 2 mats x 2 nj x 4 ks.
        short8 uf[2][2][4];
        #pragma unroll
        for (int mat = 0; mat < 2; ++mat) {
            const float* Up = mat ? Ud : Ux;
            #pragma unroll
            for (int nj = 0; nj < 2; ++nj) {
                const size_t dd = (size_t)(d0 + nj * 16 + lr);
                #pragma unroll
                for (int ks = 0; ks < 4; ++ks) {
                    const int k = ks * 32 + q * 8;
                    float4 u0 = *(const float4*)&Up[dd * RANKN + k];
                    float4 u1 = *(const float4*)&Up[dd * RANKN + k + 4];
                    short8 v;
                    v[0] = f2bf(u0.x); v[1] = f2bf(u0.y);
                    v[2] = f2bf(u0.z); v[3] = f2bf(u0.w);
                    v[4] = f2bf(u1.x); v[5] = f2bf(u1.y);
                    v[6] = f2bf(u1.z); v[7] = f2bf(u1.w);
                    uf[mat][nj][ks] = v;
                }
            }
        }
        // prefetch xvb fragments for chunk 0 (A row m = t*BBATCH + b)
        short8 afp[2][4];
        {
            const size_t row = (size_t)lr * BBATCH + b;
            #pragma unroll
            for (int mat = 0; mat < 2; ++mat)
                #pragma unroll
                for (int ks = 0; ks < 4; ++ks)
                    afp[mat][ks] = *(const short8*)
                        &xvb[row * 256 + mat * RANKN + ks * 32 + q * 8];
        }
        for (int ch = 0; ch < NCH; ++ch) {
            if (ch >= 4) { SPIN(1, ch - 3) }            // ring slot free
            const int sl = ch & 3;
            #pragma unroll
            for (int mat = 0; mat < 2; ++mat)
                #pragma unroll
                for (int nj = 0; nj < 2; ++nj) {
                    floatx4 acc = {};
                    #pragma unroll
                    for (int ks = 0; ks < 4; ++ks)
                        acc = __builtin_amdgcn_mfma_f32_16x16x32_bf16(
                            afp[mat][ks], uf[mat][nj][ks], acc, 0, 0, 0);
                    // C layout: row=q*4+r (t), col=nj*16+lr (d); interleaved
                    #pragma unroll
                    for (int r = 0; r < 4; ++r)
                        wwds[sl * (CH * PITW) + (q * 4 + r) * PITW
                             + (nj * 16 + lr) * 2 + mat] = acc[r];
                }
            SIGNAL(0, ch + 1)                           // slot ready (DS in-order)
            if (ch < NCH - 1) {                         // prefetch next chunk
                const size_t row = (size_t)((ch + 1) * CH + lr) * BBATCH + b;
                #pragma unroll
                for (int mat = 0; mat < 2; ++mat)
                    #pragma unroll
                    for (int ks = 0; ks < 4; ++ks)
                        afp[mat][ks] = *(const short8*)
                            &xvb[row * 256 + mat * RANKN + ks * 32 + q * 8];
            }
        }
    } else if (wave == 0) {
        // ---------------- chain ----------------
        // lanes 32..63 duplicate lanes 0..31 (same d, same values; duplicate
        // same-addr/same-data LDS writes are benign) — no divergence.
        const int dcol = lane & 31;
        const int d = d0 + dcol;
        const size_t xo = (size_t)b * DIMN + d;
        const float rh  = r_h[d];
        const float rd  = r_delta[d];
        const float bb  = bvec[d];
        const float bdl = b_delta[d];
        float h = h0[xo];

        for (int ch = 0; ch < NCH; ++ch) {
            SPIN(0, ch + 1)                             // wx/wd slot ready
            const int sl = ch & 3;
            float2 wv[CH];
            #pragma unroll
            for (int s = 0; s < CH; ++s)
                wv[s] = *(const float2*)
                    &wwds[sl * (CH * PITW) + s * PITW + dcol * 2];
            SIGNAL_AFTER_READS(1, ch + 1)               // free wx/wd slot
            if (ch >= 4) { SPIN(3, ch - 3) }            // h slot free
            #pragma unroll
            for (int s = 0; s < CH; ++s) {
                const float cand  = fast_tanh(rh * h + wv[s].x + bb);
                const float delta = fast_sigmoid(wv[s].y + rd * h + bdl);
                h = (1.0f - delta) * h + delta * cand;
                hsd[sl * (CH * PITH) + s * PITH + dcol] = h;
            }
            SIGNAL(2, ch + 1)                           // h ready (DS in-order)
        }
    } else {
        // ---------------- flusher ----------------
        const int dq  = lane & 7;                       // d-quad 0..7 (32 d)
        const int tof = lane >> 3;                      // t-offset 0..7
        const size_t xoffF = (size_t)b * DIMN + d0 + dq * 4;
        const float4 bg4 = *(const float4*)&b_gate[d0 + dq * 4];
        if (tof == 0) {                                 // h[0] = h0
            float4 hv = *(const float4*)&h0[xoffF];
            *(float4*)&hbuf[xoffF] = hv;
        }
        float4 xpre[2];
        #pragma unroll
        for (int jj = 0; jj < 2; ++jj)
            xpre[jj] = *(const float4*)&x[(size_t)(jj * 8 + tof) * BD + xoffF];

        for (int ch = 0; ch < NCH; ++ch) {
            SPIN(2, ch + 1)                             // h ready
            const int sl = ch & 3;
            float4 hv[2];
            #pragma unroll
            for (int jj = 0; jj < 2; ++jj)
                hv[jj] = *(const float4*)
                    &hsd[sl * (CH * PITH) + (jj * 8 + tof) * PITH + dq * 4];
            SIGNAL_AFTER_READS(3, ch + 1)               // free h slot
            const int tb = ch * CH;
            #pragma unroll
            for (int jj = 0; jj < 2; ++jj) {
                const int t = jj * 8 + tof;
                const float4 xv = xpre[jj];
                float4 ov;
                float g0 = hv[jj].x + xv.x + bg4.x;
                ov.x = hv[jj].x * (g0 * fast_sigmoid(g0));
                float g1 = hv[jj].y + xv.y + bg4.y;
                ov.y = hv[jj].y * (g1 * fast_sigmoid(g1));
                float g2 = hv[jj].z + xv.z + bg4.z;
                ov.z = hv[jj].z * (g2 * fast_sigmoid(g2));
                float g3 = hv[jj].w + xv.w + bg4.w;
                ov.w = hv[jj].w * (g3 * fast_sigmoid(g3));
                *(float4*)&obuf[(size_t)(tb + t) * BD + xoffF] = ov;
                *(float4*)&hbuf[(size_t)(tb + t + 1) * BD + xoffF] = hv[jj];
            }
            if (ch < NCH - 1) {                         // prefetch next x
                const int tn = (ch + 1) * CH;
                #pragma unroll
                for (int jj = 0; jj < 2; ++jj)
                    xpre[jj] = *(const float4*)
                        &x[(size_t)(tn + jj * 8 + tof) * BD + xoffF];
            }
        }
    }
}

// ---------------------------------------------------------------------------
extern "C" void kernel_launch(void* const* d_in, const int* in_sizes, int n_in,
                              void* d_out, int out_size, void* d_ws, size_t ws_size,
                              hipStream_t stream) {
    const float* x       = (const float*)d_in[0];   // [T,B,D]
    const float* h0      = (const float*)d_in[1];   // [B,D]
    const float* U_x     = (const float*)d_in[2];   // [D,R]
    const float* V_x     = (const float*)d_in[3];   // [R,D]
    const float* U_d     = (const float*)d_in[4];   // [D,R]
    const float* V_d     = (const float*)d_in[5];   // [R,D]
    const float* r_h     = (const float*)d_in[6];
    const float* r_delta = (const float*)d_in[7];
    const float* bvec    = (const float*)d_in[8];
    const float* b_delta = (const float*)d_in[9];
    const float* b_gate  = (const float*)d_in[10];

    float* obuf = (float*)d_out;                    // output [T,B,D]
    float* hbuf = obuf + (size_t)TT * BD;           // h [T+1,B,D]
    short* xvb  = (short*)d_ws;                     // bf16 [16384][256]: xv|xd
    short* Vb   = xvb + (size_t)TT * BBATCH * 256;  // bf16 [256][2048]

    // Phase 0: one-time V -> bf16
    prep_vb<<<256, 256, 0, stream>>>(V_x, V_d, Vb);

    // Phase 1: both low-rank projections, x read once, bf16 out.
    gemm_xv<<<TT * BBATCH / 32, 256, 0, stream>>>(x, Vb, xvb);

    // Phase 2+3: 3-wave role-pipelined fused GEMM + scan + gate, 4 blocks/CU.
    fused_scan<<<1024, 192, 0, stream>>>(xvb, x, h0, U_x, U_d,
                                         r_h, r_delta, bvec, b_delta, b_gate,
                                         obuf, hbuf);
}

// Round 7
// 506.476 us; speedup vs baseline: 1.0650x; 1.0650x over previous
//
#include <hip/hip_runtime.h>

#define DIMN 2048
#define RANKN 128
#define TT 1024
#define BBATCH 16
#define BD (BBATCH * DIMN)   // 32768 elements per timestep slice
#define CH 16                // scan chunk length (t-steps)
#define NCH (TT / CH)        // 64 chunks
#define PITW 66              // wwd row pitch in floats (32*2 interleaved + 2)
#define PITH 36              // hs row pitch in floats (16B-aligned rows)

typedef __attribute__((ext_vector_type(4))) float floatx4;
typedef __attribute__((ext_vector_type(8))) short short8;

// fp32 -> bf16 round-to-nearest-even on raw bits
__device__ __forceinline__ short f2bf(float f) {
    unsigned u = __float_as_uint(f);
    unsigned r = (u + 0x7FFFu + ((u >> 16) & 1u)) >> 16;
    return (short)r;
}
__device__ __forceinline__ float fast_sigmoid(float z) {
    return __builtin_amdgcn_rcpf(1.0f + __expf(-z));
}
__device__ __forceinline__ float fast_tanh(float z) {
    return 1.0f - 2.0f * __builtin_amdgcn_rcpf(__expf(2.0f * z) + 1.0f);
}

// ---------------------------------------------------------------------------
// Prep: V_x|V_d -> bf16 Vb[256][2048] (rows 0..127 = V_x, 128..255 = V_d).
// ---------------------------------------------------------------------------
__global__ __launch_bounds__(256)
void prep_vb(const float* __restrict__ Vx, const float* __restrict__ Vd,
             short* __restrict__ Vb) {
    const int gid = blockIdx.x * 256 + threadIdx.x;     // 0..65535
    const size_t base = (size_t)gid * 8;
    const size_t half = (size_t)RANKN * DIMN;           // 262144
    const float* src = (base < half) ? Vx : Vd;
    const size_t off = (base < half) ? base : (base - half);
    float4 a = *(const float4*)(src + off);
    float4 c = *(const float4*)(src + off + 4);
    short8 v;
    v[0] = f2bf(a.x); v[1] = f2bf(a.y); v[2] = f2bf(a.z); v[3] = f2bf(a.w);
    v[4] = f2bf(c.x); v[5] = f2bf(c.y); v[6] = f2bf(c.z); v[7] = f2bf(c.w);
    *(short8*)(Vb + base) = v;
}

// ---------------------------------------------------------------------------
// Phase 1: xvb = x @ [V_x^T | V_d^T] as bf16 [16384][256].
// BK=64 (was 32): 32 K-iterations instead of 64 -> HALF the barrier drains
// (each __syncthreads costs a full vmcnt(0) drain ~600-900 cy at 2 blocks/CU;
// this was the dominant cost, not MFMA/LDS). Same k accumulation order
// (k0 outer, kh inner, sequential) -> bit-identical numerics.
// ---------------------------------------------------------------------------
__global__ __launch_bounds__(256, 2)
void gemm_xv(const float* __restrict__ X, const short* __restrict__ Vb,
             short* __restrict__ xvb) {
    constexpr int PADK = 72;            // 64 + 8 pad shorts
    __shared__ short As[32 * PADK];
    __shared__ short Bs[2][128 * PADK];

    const int m0 = blockIdx.x * 32;
    const int tid = threadIdx.x;
    const int wave = tid >> 6;
    const int lane = tid & 63;
    const int lr = lane & 15;
    const int q  = lane >> 4;
    const int mat = wave >> 1;
    const int wn  = (wave & 1) * 64;

    floatx4 acc[2][4] = {};

    for (int k0 = 0; k0 < DIMN; k0 += 64) {
        // A: 32x64 fp32 -> bf16 (2 float4/thread)
        #pragma unroll
        for (int i = 0; i < 2; ++i) {
            int f = tid + i * 256;
            int r = f >> 4, c = (f & 15) * 4;
            float4 v = *(const float4*)(X + (size_t)(m0 + r) * DIMN + k0 + c);
            *(short4*)&As[r * PADK + c] =
                make_short4(f2bf(v.x), f2bf(v.y), f2bf(v.z), f2bf(v.w));
        }
        // B: 2 x 128 x 64 bf16 from pre-converted Vb (8 short8/thread)
        #pragma unroll
        for (int i = 0; i < 8; ++i) {
            int u = tid + i * 256;          // 0..2047
            int bm = u >> 10;
            int rem = u & 1023;
            int r = rem >> 3, c8 = (rem & 7) * 8;
            short8 v = *(const short8*)(Vb + ((size_t)bm * RANKN + r) * DIMN + k0 + c8);
            *(short8*)&Bs[bm][r * PADK + c8] = v;
        }
        __syncthreads();

        short8 af[2][2], bfr[2][4];
        #pragma unroll
        for (int kh = 0; kh < 2; ++kh) {
            #pragma unroll
            for (int mi = 0; mi < 2; ++mi)
                af[kh][mi] = *(const short8*)
                    &As[(mi * 16 + lr) * PADK + kh * 32 + q * 8];
            #pragma unroll
            for (int nj = 0; nj < 4; ++nj)
                bfr[kh][nj] = *(const short8*)
                    &Bs[mat][(wn + nj * 16 + lr) * PADK + kh * 32 + q * 8];
        }
        #pragma unroll
        for (int kh = 0; kh < 2; ++kh)
            #pragma unroll
            for (int mi = 0; mi < 2; ++mi)
                #pragma unroll
                for (int nj = 0; nj < 4; ++nj)
                    acc[mi][nj] = __builtin_amdgcn_mfma_f32_16x16x32_bf16(
                        af[kh][mi], bfr[kh][nj], acc[mi][nj], 0, 0, 0);
        __syncthreads();
    }

    #pragma unroll
    for (int mi = 0; mi < 2; ++mi)
        #pragma unroll
        for (int nj = 0; nj < 4; ++nj)
            #pragma unroll
            for (int r = 0; r < 4; ++r) {
                int row = m0 + mi * 16 + q * 4 + r;
                int col = mat * RANKN + wn + nj * 16 + lr;
                xvb[(size_t)row * 256 + col] = f2bf(acc[mi][nj][r]);
            }
}

// ---------------------------------------------------------------------------
// Phase 2+3 fused: 3-wave role pipeline, 1024 blocks. Changes vs R6 (which
// measured a FIXED ~6300 cy/chunk period regardless of blocks/CU => the
// period is a latency chain, not throughput):
//   1. TIGHT-POLL spins (no s_sleep): each handoff paid up to a sleep
//      quantum + LDS poll latency; 5 spins/chunk across roles.
//   2. DEPTH-2 prefetch: producer xvb frags (afA/afB) and flusher x
//      (xpA/xpB) are loaded TWO chunks ahead via static unroll-by-2, so
//      the ~500-900 cy global-load latency spans two periods instead of
//      sitting inside one.
// Ring depth 4, LDS-counter sync, zero barriers in the loop (proven R5/R6).
// ---------------------------------------------------------------------------
#define SPIN(ctr, tgt) \
    while (((volatile int*)cnt)[ctr] < (tgt)) {} \
    asm volatile("" ::: "memory");

#define SIGNAL(ctr, val) \
    asm volatile("" ::: "memory"); \
    if (lane == 0) ((volatile int*)cnt)[ctr] = (val);

#define SIGNAL_AFTER_READS(ctr, val) \
    asm volatile("s_waitcnt lgkmcnt(0)" ::: "memory"); \
    if (lane == 0) ((volatile int*)cnt)[ctr] = (val);

__global__ __launch_bounds__(192, 2)
void fused_scan(const short* __restrict__ xvb, const float* __restrict__ x,
                const float* __restrict__ h0,
                const float* __restrict__ Ux, const float* __restrict__ Ud,
                const float* __restrict__ r_h, const float* __restrict__ r_delta,
                const float* __restrict__ bvec, const float* __restrict__ b_delta,
                const float* __restrict__ b_gate,
                float* __restrict__ obuf, float* __restrict__ hbuf) {
    __shared__ float wwds[4 * CH * PITW];   // [slot][t][dcol*2 + mat]
    __shared__ float hsd [4 * CH * PITH];   // [slot][t][dcol]
    __shared__ int cnt[4];                  // 0:fill 1:wfree 2:hready 3:hfree

    const int id   = blockIdx.x;            // 0..1023
    const int xcd  = id & 7;
    const int slot = id >> 3;               // 0..127
    const int b  = xcd * 2 + (slot & 1);
    const int d0 = (slot >> 1) * 32;

    const int tid  = threadIdx.x;
    const int wave = tid >> 6;
    const int lane = tid & 63;
    const int lr = lane & 15;
    const int q  = lane >> 4;

    if (tid == 0) { cnt[0] = 0; cnt[1] = 0; cnt[2] = 0; cnt[3] = 0; }
    __syncthreads();                        // the only barrier

    if (wave == 1) {
        // ---------------- producer ----------------
        short8 uf[2][2][4];                 // U frags [mat][nj][ks]
        #pragma unroll
        for (int mat = 0; mat < 2; ++mat) {
            const float* Up = mat ? Ud : Ux;
            #pragma unroll
            for (int nj = 0; nj < 2; ++nj) {
                const size_t dd = (size_t)(d0 + nj * 16 + lr);
                #pragma unroll
                for (int ks = 0; ks < 4; ++ks) {
                    const int k = ks * 32 + q * 8;
                    float4 u0 = *(const float4*)&Up[dd * RANKN + k];
                    float4 u1 = *(const float4*)&Up[dd * RANKN + k + 4];
                    short8 v;
                    v[0] = f2bf(u0.x); v[1] = f2bf(u0.y);
                    v[2] = f2bf(u0.z); v[3] = f2bf(u0.w);
                    v[4] = f2bf(u1.x); v[5] = f2bf(u1.y);
                    v[6] = f2bf(u1.z); v[7] = f2bf(u1.w);
                    uf[mat][nj][ks] = v;
                }
            }
        }
        short8 afA[2][4], afB[2][4];        // xvb A-frag 2-deep prefetch
        auto ldaf = [&](int ch, short8 (&af)[2][4]) {
            const size_t row = (size_t)(ch * CH + lr) * BBATCH + b;
            #pragma unroll
            for (int mat = 0; mat < 2; ++mat)
                #pragma unroll
                for (int ks = 0; ks < 4; ++ks)
                    af[mat][ks] = *(const short8*)
                        &xvb[row * 256 + mat * RANKN + ks * 32 + q * 8];
        };
        auto fill = [&](int ch, short8 (&af)[2][4]) {
            const int sl = ch & 3;
            #pragma unroll
            for (int mat = 0; mat < 2; ++mat)
                #pragma unroll
                for (int nj = 0; nj < 2; ++nj) {
                    floatx4 acc = {};
                    #pragma unroll
                    for (int ks = 0; ks < 4; ++ks)
                        acc = __builtin_amdgcn_mfma_f32_16x16x32_bf16(
                            af[mat][ks], uf[mat][nj][ks], acc, 0, 0, 0);
                    #pragma unroll
                    for (int r = 0; r < 4; ++r)
                        wwds[sl * (CH * PITW) + (q * 4 + r) * PITW
                             + (nj * 16 + lr) * 2 + mat] = acc[r];
                }
        };
        ldaf(0, afA);
        ldaf(1, afB);
        for (int ch = 0; ch < NCH; ch += 2) {
            if (ch >= 4) { SPIN(1, ch - 3) }
            fill(ch, afA);
            SIGNAL(0, ch + 1)
            if (ch + 2 < NCH) ldaf(ch + 2, afA);
            if (ch + 1 >= 4) { SPIN(1, ch - 2) }
            fill(ch + 1, afB);
            SIGNAL(0, ch + 2)
            if (ch + 3 < NCH) ldaf(ch + 3, afB);
        }
    } else if (wave == 0) {
        // ---------------- chain ----------------
        const int dcol = lane & 31;         // lanes 32..63 duplicate 0..31
        const int d = d0 + dcol;
        const size_t xo = (size_t)b * DIMN + d;
        const float rh  = r_h[d];
        const float rd  = r_delta[d];
        const float bb  = bvec[d];
        const float bdl = b_delta[d];
        float h = h0[xo];

        for (int ch = 0; ch < NCH; ++ch) {
            SPIN(0, ch + 1)                 // wx/wd slot ready
            const int sl = ch & 3;
            float2 wv[CH];
            #pragma unroll
            for (int s = 0; s < CH; ++s)
                wv[s] = *(const float2*)
                    &wwds[sl * (CH * PITW) + s * PITW + dcol * 2];
            SIGNAL_AFTER_READS(1, ch + 1)   // free wx/wd slot
            if (ch >= 4) { SPIN(3, ch - 3) }// h slot free
            #pragma unroll
            for (int s = 0; s < CH; ++s) {
                const float cand  = fast_tanh(rh * h + wv[s].x + bb);
                const float delta = fast_sigmoid(wv[s].y + rd * h + bdl);
                h = (1.0f - delta) * h + delta * cand;
                hsd[sl * (CH * PITH) + s * PITH + dcol] = h;
            }
            SIGNAL(2, ch + 1)               // h ready (DS in-order)
        }
    } else {
        // ---------------- flusher ----------------
        const int dq  = lane & 7;           // d-quad 0..7 (32 d)
        const int tof = lane >> 3;          // t-offset 0..7
        const size_t xoffF = (size_t)b * DIMN + d0 + dq * 4;
        const float4 bg4 = *(const float4*)&b_gate[d0 + dq * 4];
        if (tof == 0) {                     // h[0] = h0
            float4 hv = *(const float4*)&h0[xoffF];
            *(float4*)&hbuf[xoffF] = hv;
        }
        float4 xpA[2], xpB[2];              // x 2-deep prefetch
        auto ldx = [&](int ch, float4 (&xp)[2]) {
            const int tn = ch * CH;
            #pragma unroll
            for (int jj = 0; jj < 2; ++jj)
                xp[jj] = *(const float4*)
                    &x[(size_t)(tn + jj * 8 + tof) * BD + xoffF];
        };
        auto flush = [&](int ch, float4 (&xp)[2]) {
            SPIN(2, ch + 1)                 // h ready
            const int sl = ch & 3;
            float4 hv[2];
            #pragma unroll
            for (int jj = 0; jj < 2; ++jj)
                hv[jj] = *(const float4*)
                    &hsd[sl * (CH * PITH) + (jj * 8 + tof) * PITH + dq * 4];
            SIGNAL_AFTER_READS(3, ch + 1)   // free h slot
            const int tb = ch * CH;
            #pragma unroll
            for (int jj = 0; jj < 2; ++jj) {
                const int t = jj * 8 + tof;
                const float4 xv = xp[jj];
                float4 ov;
                float g0 = hv[jj].x + xv.x + bg4.x;
                ov.x = hv[jj].x * (g0 * fast_sigmoid(g0));
                float g1 = hv[jj].y + xv.y + bg4.y;
                ov.y = hv[jj].y * (g1 * fast_sigmoid(g1));
                float g2 = hv[jj].z + xv.z + bg4.z;
                ov.z = hv[jj].z * (g2 * fast_sigmoid(g2));
                float g3 = hv[jj].w + xv.w + bg4.w;
                ov.w = hv[jj].w * (g3 * fast_sigmoid(g3));
                *(float4*)&obuf[(size_t)(tb + t) * BD + xoffF] = ov;
                *(float4*)&hbuf[(size_t)(tb + t + 1) * BD + xoffF] = hv[jj];
            }
        };
        ldx(0, xpA);
        ldx(1, xpB);
        for (int ch = 0; ch < NCH; ch += 2) {
            flush(ch, xpA);
            if (ch + 2 < NCH) ldx(ch + 2, xpA);
            flush(ch + 1, xpB);
            if (ch + 3 < NCH) ldx(ch + 3, xpB);
        }
    }
}

// ---------------------------------------------------------------------------
extern "C" void kernel_launch(void* const* d_in, const int* in_sizes, int n_in,
                              void* d_out, int out_size, void* d_ws, size_t ws_size,
                              hipStream_t stream) {
    const float* x       = (const float*)d_in[0];   // [T,B,D]
    const float* h0      = (const float*)d_in[1];   // [B,D]
    const float* U_x     = (const float*)d_in[2];   // [D,R]
    const float* V_x     = (const float*)d_in[3];   // [R,D]
    const float* U_d     = (const float*)d_in[4];   // [D,R]
    const float* V_d     = (const float*)d_in[5];   // [R,D]
    const float* r_h     = (const float*)d_in[6];
    const float* r_delta = (const float*)d_in[7];
    const float* bvec    = (const float*)d_in[8];
    const float* b_delta = (const float*)d_in[9];
    const float* b_gate  = (const float*)d_in[10];

    float* obuf = (float*)d_out;                    // output [T,B,D]
    float* hbuf = obuf + (size_t)TT * BD;           // h [T+1,B,D]
    short* xvb  = (short*)d_ws;                     // bf16 [16384][256]: xv|xd
    short* Vb   = xvb + (size_t)TT * BBATCH * 256;  // bf16 [256][2048]

    // Phase 0: one-time V -> bf16
    prep_vb<<<256, 256, 0, stream>>>(V_x, V_d, Vb);

    // Phase 1: both low-rank projections, x read once, bf16 out (BK=64).
    gemm_xv<<<TT * BBATCH / 32, 256, 0, stream>>>(x, Vb, xvb);

    // Phase 2+3: 3-wave role-pipelined fused GEMM + scan + gate.
    fused_scan<<<1024, 192, 0, stream>>>(xvb, x, h0, U_x, U_d,
                                         r_h, r_delta, bvec, b_delta, b_gate,
                                         obuf, hbuf);
}